// Round 15
// baseline (4432.836 us; speedup 1.0000x reference)
//
#include <hip/hip_runtime.h>
#include <hip/hip_bf16.h>
#include <stdint.h>

// ContainedLSTM: B=128, S=1024, I=256, H=256.
// xw = x@W_ih^T: split-bf16 (Ootomo) MFMA GEMM -> fp32-grade, chunked in ws.
// Recurrence: R7/R14 structure: 32 WGs = 8 groups x 4 j-quarters, W_hh*gamma
// f16 parked in AGPRs, h as f16 hi+lo LDS planes, batch-sweep tagged poll.
// R15 change: 4 f16 values per u64 with 1-BIT PARITY tags in each f16's
// mantissa LSB (slot reused every 2 steps -> consecutive uses alternate
// parity ((tg+1)>>1)&1; two-deep pipeline bounds staleness to 1 generation).
// Publish via R8's HW-verified 4x4 quad transpose: 1 store/thread; gather
// 3 loads/thread. UC ops/block/step ~2.8k -> ~1.3k (R14 confirmed ~1ns/op).

#define Bb 128
#define Ss 1024
#define Ii 256
#define Hh 256
#define G4v 1024
#define EPSF 1e-5f

typedef __bf16 bf16;
typedef _Float16 f16;
typedef __attribute__((ext_vector_type(8))) __bf16 bf16x8;
typedef __attribute__((ext_vector_type(4))) _Float16 f16x4;
typedef __attribute__((ext_vector_type(8))) _Float16 f16x8;
typedef __attribute__((ext_vector_type(4))) float f32x4;
typedef unsigned int u32;
typedef unsigned long long u64;

static __device__ __forceinline__ f32x4 mfma16b(bf16x8 a, bf16x8 b, f32x4 c) {
  return __builtin_amdgcn_mfma_f32_16x16x32_bf16(a, b, c, 0, 0, 0);
}
static __device__ __forceinline__ f32x4 mfma16h(f16x8 a, f16x8 b, f32x4 c) {
  return __builtin_amdgcn_mfma_f32_16x16x32_f16(a, b, c, 0, 0, 0);
}
static __device__ __forceinline__ float sigm(float x) { return 1.0f / (1.0f + __expf(-x)); }
static __device__ __forceinline__ float tanhf_(float x) {
  float e = __expf(-2.0f * fabsf(x));
  float t = (1.0f - e) / (1.0f + e);
  return x < 0.0f ? -t : t;
}
static __device__ __forceinline__ unsigned short ush(f16 h) {
  return __builtin_bit_cast(unsigned short, h);
}
static __device__ __forceinline__ f16 hus(unsigned short u) {
  return __builtin_bit_cast(f16, u);
}

// ---------------- prep kernels ----------------
__global__ void k_conv_wih(const float* __restrict__ W, bf16* __restrict__ hi,
                           bf16* __restrict__ lo) {
  int i = (blockIdx.x * 256 + threadIdx.x) * 4;
  f32x4 v = *(const f32x4*)(W + i);
#pragma unroll
  for (int j = 0; j < 4; ++j) {
    bf16 hh = (bf16)v[j];
    hi[i + j] = hh;
    lo[i + j] = (bf16)(v[j] - (float)hh);
  }
}

// Wtil = W_hh * gamma -> single f16 plane, fragment-linear:
// Wf[(ntg*8+kt)*64 + lane][8] = Wtil[g=ntg*16+(lane&15)][k=kt*32+(lane>>4)*8+j]
__global__ void k_prep_whh(const float* __restrict__ W, const float* __restrict__ gamma,
                           f16* __restrict__ Wf) {
  int tid = blockIdx.x * 256 + threadIdx.x;  // 0..32767
  int lane = tid & 63;
  int fk = tid >> 6;
  int ntg = fk >> 3, kt = fk & 7;
  int g = ntg * 16 + (lane & 15);
  int k = kt * 32 + ((lane >> 4) << 3);
  f16x8 r;
#pragma unroll
  for (int j = 0; j < 8; ++j) r[j] = (f16)(W[g * Hh + k + j] * gamma[k + j]);
  *(f16x8*)(Wf + (size_t)tid * 8) = r;
}

__global__ void k_prep_rd(const float* __restrict__ W, const float* __restrict__ gamma,
                          const float* __restrict__ beta, const float* __restrict__ bih,
                          const float* __restrict__ bhh, float* __restrict__ RD) {
  int g = blockIdx.x * 256 + threadIdx.x;  // 1024 total
  float r = 0.f, d = 0.f;
  for (int k = 0; k < Hh; ++k) {
    float w = W[g * Hh + k];
    r += w * gamma[k];
    d += w * beta[k];
  }
  RD[2 * g] = r;
  RD[2 * g + 1] = d + bih[g] + bhh[g];
}

// ---------------- xw GEMM (split-bf16, unchanged) ----------------
__global__ __launch_bounds__(256, 2) void k_gemm(const float* __restrict__ x,
                                                 const bf16* __restrict__ Whi,
                                                 const bf16* __restrict__ Wlo,
                                                 float* __restrict__ xw,
                                                 int t0, int Tc, int ntb) {
  __shared__ bf16 Bs[2][128 * 128];
  int bid = blockIdx.x;
  int b = bid & 127;
  int r2 = bid >> 7;
  int tb = r2 % ntb;
  int gt = r2 / ntb;
  int g0 = gt * 128;
  int tid = threadIdx.x, w = tid >> 6, lane = tid & 63;
  int li = lane & 15, lg = lane >> 4;
  char* BsB = (char*)Bs;
  int tbase = tb * 128 + 32 * w;
  f32x4 acc[2][8];
#pragma unroll
  for (int mt = 0; mt < 2; ++mt)
#pragma unroll
    for (int nt = 0; nt < 8; ++nt) acc[mt][nt] = (f32x4){0.f, 0.f, 0.f, 0.f};

  for (int kp = 0; kp < 2; ++kp) {
#pragma unroll
    for (int it = 0; it < 8; ++it) {
      int p = it * 4096 + tid * 16;
      int row = p >> 8, colb = p & 255;
      size_t goff = (size_t)(g0 + row) * 512 + kp * 256 + colb;
      int dst = row * 256 + (colb ^ ((row & 7) << 4));
      *(bf16x8*)(BsB + dst) = *(const bf16x8*)((const char*)Whi + goff);
      *(bf16x8*)(BsB + 32768 + dst) = *(const bf16x8*)((const char*)Wlo + goff);
    }
    __syncthreads();
#pragma unroll
    for (int kt = 0; kt < 4; ++kt) {
      int kl = kt * 32 + lg * 8;
      int kgl = kp * 128 + kl;
      bf16x8 ah[2], al[2];
#pragma unroll
      for (int mt = 0; mt < 2; ++mt) {
        int t = t0 + tbase + 16 * mt + li;
        const float* xp = x + ((size_t)b * Ss + t) * Ii + kgl;
        f32x4 f0 = *(const f32x4*)xp;
        f32x4 f1 = *(const f32x4*)(xp + 4);
        bf16x8 hv, lv;
#pragma unroll
        for (int j = 0; j < 4; ++j) {
          bf16 h0 = (bf16)f0[j];
          hv[j] = h0;
          lv[j] = (bf16)(f0[j] - (float)h0);
          bf16 h1 = (bf16)f1[j];
          hv[4 + j] = h1;
          lv[4 + j] = (bf16)(f1[j] - (float)h1);
        }
        ah[mt] = hv;
        al[mt] = lv;
      }
#pragma unroll
      for (int nt = 0; nt < 8; ++nt) {
        int grow = nt * 16 + li;
        int off = grow * 256 + ((kl * 2) ^ ((grow & 7) << 4));
        bf16x8 bh = *(const bf16x8*)(BsB + off);
        bf16x8 bl = *(const bf16x8*)(BsB + 32768 + off);
#pragma unroll
        for (int mt = 0; mt < 2; ++mt) {
          acc[mt][nt] = mfma16b(ah[mt], bh, acc[mt][nt]);
          acc[mt][nt] = mfma16b(ah[mt], bl, acc[mt][nt]);
          acc[mt][nt] = mfma16b(al[mt], bh, acc[mt][nt]);
        }
      }
    }
    __syncthreads();
  }
#pragma unroll
  for (int mt = 0; mt < 2; ++mt)
#pragma unroll
    for (int nt = 0; nt < 8; ++nt)
#pragma unroll
      for (int r = 0; r < 4; ++r) {
        int tl = tbase + 16 * mt + lg * 4 + r;
        int g = g0 + nt * 16 + li;
        xw[((size_t)b * Tc + tl) * G4v + g] = acc[mt][nt][r];
      }
}

// ---------------- recurrence (quarter-split, parity-packed u64) ----------
// grid: 32 blocks, bid = q*8 + grp; block 256 thr / 4 waves.
__global__ __launch_bounds__(256, 1) void k_recur(
    const f16* __restrict__ Wf, const float* __restrict__ xw,
    const int* __restrict__ mask, const float* __restrict__ RD,
    float* __restrict__ st_h, float* __restrict__ st_c, float* __restrict__ st_o,
    u64* pub, float* __restrict__ out, int t0, int Tc, int first, int last) {
  __shared__ f16 hbH[16 * 256];     // h hi plane, byte ^= (row&7)<<4 swizzle
  __shared__ f16 hbL[16 * 256];     // h lo plane
  __shared__ float murs[2][16][2];  // (mu*rs, rs) per row, parity-buffered
  __shared__ float2 spw[4][16];     // per-wave per-row own-slice partials
  __shared__ float spart[16][16][2];  // init-path only
  int bid = blockIdx.x;
  int grp = bid & 7, q = bid >> 3;
  int tid = threadIdx.x, w = tid >> 6, lane = tid & 63;
  int li = lane & 15, lg = lane >> 4;
  int b0 = grp * 16;
  int jloc = (q * 4 + w) * 16 + li;
  char* hbHB = (char*)hbH;
  char* hbLB = (char*)hbL;

  // park this wave's W-quarter (single f16 plane, 128 regs) in AGPRs
  f16x8 wp[4][8];
#pragma unroll
  for (int c = 0; c < 4; ++c)
#pragma unroll
    for (int kt = 0; kt < 8; ++kt) {
      int ntg = c * 16 + q * 4 + w;
      wp[c][kt] = *(const f16x8*)(Wf + ((size_t)(ntg * 8 + kt) * 64 + lane) * 8);
      asm volatile("" : "+a"(wp[c][kt]));
    }
  float Rr[4], Dd[4];
#pragma unroll
  for (int c = 0; c < 4; ++c) {
    int g = c * 256 + jloc;
    Rr[c] = RD[2 * g];
    Dd[c] = RD[2 * g + 1];
  }

  float cst[4], ost[4];
  if (first) {
#pragma unroll
    for (int i = 0; i < 16; ++i) {
      hbH[tid * 16 + i] = (f16)0.0f;
      hbL[tid * 16 + i] = (f16)0.0f;
    }
#pragma unroll
    for (int r = 0; r < 4; ++r) { cst[r] = 0.f; ost[r] = 0.f; }
    if (tid < 16) { murs[0][tid][0] = 0.f; murs[0][tid][1] = rsqrtf(EPSF); }
  } else {
    int row = tid >> 4, cs = tid & 15, jseg = cs * 16;
    float s = 0.f, ss = 0.f;
#pragma unroll
    for (int i = 0; i < 16; ++i) {
      float v = st_h[(size_t)(b0 + row) * Hh + jseg + i];
      s += v;
      ss += v * v;
      f16 hh = (f16)v;
      int boff = row * 512 + (((jseg + i) * 2) ^ ((row & 7) << 4));
      *(f16*)(hbHB + boff) = hh;
      *(f16*)(hbLB + boff) = (f16)(v - (float)hh);
    }
    spart[row][cs][0] = s;
    spart[row][cs][1] = ss;
#pragma unroll
    for (int r = 0; r < 4; ++r) {
      int m = lg * 4 + r;
      cst[r] = st_c[(size_t)(b0 + m) * Hh + jloc];
      ost[r] = st_o[(size_t)(b0 + m) * Hh + jloc];
    }
    __syncthreads();
    if (tid < 16) {
      float s2 = 0.f, ss2 = 0.f;
#pragma unroll
      for (int i = 0; i < 16; ++i) { s2 += spart[tid][i][0]; ss2 += spart[tid][i][1]; }
      float mu = s2 * (1.f / 256.f);
      float var = ss2 * (1.f / 256.f) - mu * mu;
      float rs = rsqrtf(var + EPSF);
      murs[0][tid][0] = mu * rs;
      murs[0][tid][1] = rs;
    }
  }
  __syncthreads();

  // preload xw/mask for tl=0
  float xwv[4][4];
  int mk[4];
#pragma unroll
  for (int c = 0; c < 4; ++c)
#pragma unroll
    for (int r = 0; r < 4; ++r)
      xwv[c][r] = xw[((size_t)(b0 + lg * 4 + r) * Tc + 0) * G4v + c * 256 + jloc];
#pragma unroll
  for (int r = 0; r < 4; ++r) mk[r] = mask[(size_t)(b0 + lg * 4 + r) * Ss + t0];

  int grow = tid >> 4, gcg = tid & 15;  // gather role: row, col-group (4 cols)
  int bq = li & 3;                      // quad index for publish transpose
  const u64 PMASK = 0x0001000100010001ull;

  for (int tl = 0; tl < Tc; ++tl) {
    int tg = t0 + tl;
    int slot = (tg + 1) & 1;
    u32 wpar = ((u32)(tg + 1) >> 1) & 1;
    u64 wantp = wpar ? PMASK : 0;

    // P1: two 8-deep MFMA chains per gate: (h_hi + h_lo) x W_f16
    f32x4 a0[4], a1[4];
#pragma unroll
    for (int c = 0; c < 4; ++c) {
      a0[c] = (f32x4){0.f, 0.f, 0.f, 0.f};
      a1[c] = (f32x4){0.f, 0.f, 0.f, 0.f};
    }
#pragma unroll
    for (int kt = 0; kt < 8; ++kt) {
      int aoff = li * 512 + (((kt * 32 + lg * 8) * 2) ^ ((li & 7) << 4));
      f16x8 ah = *(const f16x8*)(hbHB + aoff);
      f16x8 al = *(const f16x8*)(hbLB + aoff);
#pragma unroll
      for (int c = 0; c < 4; ++c) {
        a0[c] = mfma16h(ah, wp[c][kt], a0[c]);
        a1[c] = mfma16h(al, wp[c][kt], a1[c]);
      }
    }
    float mrs[4], rsv[4];
#pragma unroll
    for (int r = 0; r < 4; ++r) {
      int m = lg * 4 + r;
      mrs[r] = murs[tl & 1][m][0];
      rsv[r] = murs[tl & 1][m][1];
    }
    __syncthreads();  // SYNC_A: all waves done reading hb (state t) + murs

    // P2: gates -> c,h,out; own hb slice (hi+lo exact)
    float hnew[4];
#pragma unroll
    for (int r = 0; r < 4; ++r) {
      float i_ = (a0[0][r] + a1[0][r]) * rsv[r] - mrs[r] * Rr[0] + Dd[0] + xwv[0][r];
      float f_ = (a0[1][r] + a1[1][r]) * rsv[r] - mrs[r] * Rr[1] + Dd[1] + xwv[1][r];
      float g_ = (a0[2][r] + a1[2][r]) * rsv[r] - mrs[r] * Rr[2] + Dd[2] + xwv[2][r];
      float o_ = (a0[3][r] + a1[3][r]) * rsv[r] - mrs[r] * Rr[3] + Dd[3] + xwv[3][r];
      float cn = sigm(f_) * cst[r] + sigm(i_) * tanhf_(g_);
      float hn = sigm(o_) * tanhf_(cn);
      cst[r] = cn;
      ost[r] = mk[r] ? ost[r] : hn;
      hnew[r] = hn;
      int m = lg * 4 + r;
      f16 hh = (f16)hn;
      int boff = m * 512 + ((jloc * 2) ^ ((m & 7) << 4));
      *(f16*)(hbHB + boff) = hh;
      *(f16*)(hbLB + boff) = (f16)(hn - (float)hh);
    }
    // publish: 4x4 quad transpose (R8-verified) -> lane bq holds row
    // m2=lg*4+bq, cols colq..colq+3; pack 4 parity-LSB f16 into ONE u64.
    {
      float tp[4];
#pragma unroll
      for (int r = 0; r < 4; ++r) tp[r] = hnew[r];
      {
        float s01 = (bq & 1) ? tp[0] : tp[1];
        float r01 = __shfl_xor(s01, 1);
        if (bq & 1) tp[0] = r01; else tp[1] = r01;
        float s23 = (bq & 1) ? tp[2] : tp[3];
        float r23 = __shfl_xor(s23, 1);
        if (bq & 1) tp[2] = r23; else tp[3] = r23;
        float s02 = (bq & 2) ? tp[0] : tp[2];
        float r02 = __shfl_xor(s02, 2);
        if (bq & 2) tp[0] = r02; else tp[2] = r02;
        float s13 = (bq & 2) ? tp[1] : tp[3];
        float r13 = __shfl_xor(s13, 2);
        if (bq & 2) tp[1] = r13; else tp[3] = r13;
      }
      u64 pv = 0;
#pragma unroll
      for (int a = 0; a < 4; ++a) {
        u32 hw = (u32)ush((f16)tp[a]);
        hw = (hw & ~1u) | wpar;
        pv |= (u64)hw << (16 * a);
      }
      u64* ph = pub + (size_t)(slot * 32 + bid) * 256;
      int m2 = lg * 4 + bq;
      int cg = w * 4 + ((li & 12) >> 2);
      __hip_atomic_store(&ph[m2 * 16 + cg], pv, __ATOMIC_RELAXED,
                         __HIP_MEMORY_SCOPE_AGENT);
    }

    // issue first gather sweep (3 partners x 1 u64 = 4 cols per thread each)
    u64 gv[3];
    const u64* srcs[3];
#pragma unroll
    for (int pi = 0; pi < 3; ++pi) {
      int qq = (q + 1 + pi) & 3;
      int pbid = qq * 8 + grp;
      srcs[pi] = pub + (size_t)(slot * 32 + pbid) * 256 + grow * 16 + gcg;
      gv[pi] = __hip_atomic_load(srcs[pi], __ATOMIC_RELAXED, __HIP_MEMORY_SCOPE_AGENT);
    }

    // own-slice LN partials (shfl over the 16 li lanes)
    {
      float sr[4], qr[4];
#pragma unroll
      for (int r = 0; r < 4; ++r) { sr[r] = hnew[r]; qr[r] = hnew[r] * hnew[r]; }
#pragma unroll
      for (int msk = 1; msk < 16; msk <<= 1)
#pragma unroll
        for (int r = 0; r < 4; ++r) {
          sr[r] += __shfl_xor(sr[r], msk);
          qr[r] += __shfl_xor(qr[r], msk);
        }
      if (li == 0)
#pragma unroll
        for (int r = 0; r < 4; ++r) spw[w][lg * 4 + r] = make_float2(sr[r], qr[r]);
    }
    if (tl == Tc - 1) {
#pragma unroll
      for (int r = 0; r < 4; ++r) {
        int m = lg * 4 + r;
        st_h[(size_t)(b0 + m) * Hh + jloc] = hnew[r];
        st_c[(size_t)(b0 + m) * Hh + jloc] = cst[r];
        st_o[(size_t)(b0 + m) * Hh + jloc] = ost[r];
      }
      if (last) {
#pragma unroll
        for (int r = 0; r < 4; ++r) out[(size_t)(b0 + lg * 4 + r) * Hh + jloc] = ost[r];
      }
    }
    // prefetch next xw/mask (overlaps the poll window)
    {
      int tln = (tl + 1 < Tc) ? tl + 1 : Tc - 1;
#pragma unroll
      for (int c = 0; c < 4; ++c)
#pragma unroll
        for (int r = 0; r < 4; ++r)
          xwv[c][r] = xw[((size_t)(b0 + lg * 4 + r) * Tc + tln) * G4v + c * 256 + jloc];
#pragma unroll
      for (int r = 0; r < 4; ++r) mk[r] = mask[(size_t)(b0 + lg * 4 + r) * Ss + t0 + tln];
    }

    // P3: batch-sweep poll on the 3 parity-tagged u64
    {
      u32 bad = 0;
#pragma unroll
      for (int pi = 0; pi < 3; ++pi) {
        u64 d = (gv[pi] & PMASK) ^ wantp;
        bad |= (u32)d | (u32)(d >> 32);
      }
      int cnt = 0;
      while (bad) {
#pragma unroll
        for (int pi = 0; pi < 3; ++pi)
          gv[pi] = __hip_atomic_load(srcs[pi], __ATOMIC_RELAXED,
                                     __HIP_MEMORY_SCOPE_AGENT);
        bad = 0;
#pragma unroll
        for (int pi = 0; pi < 3; ++pi) {
          u64 d = (gv[pi] & PMASK) ^ wantp;
          bad |= (u32)d | (u32)(d >> 32);
        }
        if (++cnt > (1 << 20)) break;  // hang insurance
      }
    }
    // unpack -> hbH (f16), zero hbL; accumulate remote LN partials in regs
    float su = 0.f, qu = 0.f;
#pragma unroll
    for (int pi = 0; pi < 3; ++pi) {
      int qq = (q + 1 + pi) & 3;
      int j0 = qq * 64 + gcg * 4;
      int boff = grow * 512 + ((j0 * 2) ^ ((grow & 7) << 4));
      f16x4 h4;
#pragma unroll
      for (int a = 0; a < 4; ++a) h4[a] = hus((unsigned short)(gv[pi] >> (16 * a)));
      f16x4 z4 = (f16x4){(f16)0.f, (f16)0.f, (f16)0.f, (f16)0.f};
      *(f16x4*)(hbHB + boff) = h4;
      *(f16x4*)(hbLB + boff) = z4;
#pragma unroll
      for (int e = 0; e < 4; ++e) {
        float f = (float)h4[e];
        su += f;
        qu += f * f;
      }
    }
#pragma unroll
    for (int msk = 1; msk < 16; msk <<= 1) {
      su += __shfl_xor(su, msk);
      qu += __shfl_xor(qu, msk);
    }
    __syncthreads();  // SYNC_D: hb complete; spw visible
    if (li == 0) {
      float s = su + spw[0][grow].x + spw[1][grow].x + spw[2][grow].x + spw[3][grow].x;
      float ss2 = qu + spw[0][grow].y + spw[1][grow].y + spw[2][grow].y + spw[3][grow].y;
      float mu = s * (1.f / 256.f);
      float var = ss2 * (1.f / 256.f) - mu * mu;
      float rs = rsqrtf(var + EPSF);
      murs[(tl + 1) & 1][grow][0] = mu * rs;
      murs[(tl + 1) & 1][grow][1] = rs;
    }
    __syncthreads();  // SYNC_E: murs write visible before next P1 reads it
  }
}

// ---------------- host ----------------
extern "C" void kernel_launch(void* const* d_in, const int* in_sizes, int n_in,
                              void* d_out, int out_size, void* d_ws, size_t ws_size,
                              hipStream_t stream) {
  (void)in_sizes; (void)n_in; (void)out_size;
  const float* x = (const float*)d_in[0];
  const int* mask = (const int*)d_in[1];
  const float* Wih = (const float*)d_in[2];
  const float* Whh = (const float*)d_in[3];
  const float* bih = (const float*)d_in[4];
  const float* bhh = (const float*)d_in[5];
  const float* gamma = (const float*)d_in[6];
  const float* beta = (const float*)d_in[7];
  float* outp = (float*)d_out;
  char* ws = (char*)d_ws;

  const size_t extra = 3 * (512u << 10) + (8u << 10) + 3 * (128u << 10) +
                       (256u << 10) + (64u << 10);
  int Tc = 128;
  if (ws_size >= (size_t)1024 * 524288 + extra) Tc = 1024;
  else if (ws_size >= (size_t)512 * 524288 + extra) Tc = 512;
  else if (ws_size >= (size_t)256 * 524288 + extra) Tc = 256;

  size_t o = 0;
  auto take = [&](size_t bytes) { size_t r = o; o += (bytes + 255) & ~(size_t)255; return r; };
  size_t xw_off = take((size_t)Bb * Tc * G4v * 4);
  size_t wihh_off = take(512u << 10);
  size_t wihl_off = take(512u << 10);
  size_t whh_off = take(512u << 10);
  size_t rd_off = take(8u << 10);
  size_t sth_off = take(128u << 10);
  size_t stc_off = take(128u << 10);
  size_t sto_off = take(128u << 10);
  size_t pub_off = take(256u << 10);

  bf16* wihh = (bf16*)(ws + wihh_off);
  bf16* wihl = (bf16*)(ws + wihl_off);
  f16* whhf = (f16*)(ws + whh_off);
  float* rd = (float*)(ws + rd_off);
  float* xwp = (float*)(ws + xw_off);
  float* sth = (float*)(ws + sth_off);
  float* stc = (float*)(ws + stc_off);
  float* sto = (float*)(ws + sto_off);
  u64* pubh = (u64*)(ws + pub_off);

  // init pub to parity-1 pattern (0x0101... -> every f16 LSB = 1); first
  // wanted parity is 0, so init never false-validates.
  hipMemsetAsync(pubh, 0x01, 256u << 10, stream);
  k_conv_wih<<<dim3(256), dim3(256), 0, stream>>>(Wih, wihh, wihl);
  k_prep_whh<<<dim3(128), dim3(256), 0, stream>>>(Whh, gamma, whhf);
  k_prep_rd<<<dim3(4), dim3(256), 0, stream>>>(Whh, gamma, beta, bih, bhh, rd);

  int nchunk = Ss / Tc;
  int ntb = Tc / 128;
  for (int ci = 0; ci < nchunk; ++ci) {
    int t0 = ci * Tc;
    k_gemm<<<dim3(8 * ntb * 128), dim3(256), 0, stream>>>(x, wihh, wihl, xwp, t0, Tc, ntb);
    k_recur<<<dim3(32), dim3(256), 0, stream>>>(whhf, xwp, mask, rd, sth, stc, sto,
                                                pubh, outp, t0, Tc,
                                                ci == 0 ? 1 : 0, ci == nchunk - 1 ? 1 : 0);
  }
}

// Round 16
// 3863.567 us; speedup vs baseline: 1.1473x; 1.1473x over previous
//
#include <hip/hip_runtime.h>
#include <hip/hip_bf16.h>
#include <stdint.h>

// ContainedLSTM: B=128, S=1024, I=256, H=256.   == R14 (best: 3872us) ==
// xw = x@W_ih^T: split-bf16 (Ootomo) MFMA GEMM -> fp32-grade, chunked in ws.
// Recurrence: 32 WGs = 8 groups x 4 j-quarters, W_hh*gamma f16 parked in
// AGPRs, h as f16 hi+lo LDS planes, self-validating tagged u64 exchange
// (paired packing: tag32|f16_even|f16_odd), batch-sweep poll, SYNC_E closes
// the murs race. R15's 4-per-u64 parity packing REGRESSED (cost is per
// coherence-point transaction, not per byte: strided 32B store chunks kept
// txn count constant) -> reverted to R14. This is the latency floor:
// step = 1.2us compute + ~2.3us coherence-point exchange latency.

#define Bb 128
#define Ss 1024
#define Ii 256
#define Hh 256
#define G4v 1024
#define EPSF 1e-5f

typedef __bf16 bf16;
typedef _Float16 f16;
typedef __attribute__((ext_vector_type(8))) __bf16 bf16x8;
typedef __attribute__((ext_vector_type(4))) _Float16 f16x4;
typedef __attribute__((ext_vector_type(8))) _Float16 f16x8;
typedef __attribute__((ext_vector_type(4))) float f32x4;
typedef unsigned int u32;
typedef unsigned long long u64;

static __device__ __forceinline__ f32x4 mfma16b(bf16x8 a, bf16x8 b, f32x4 c) {
  return __builtin_amdgcn_mfma_f32_16x16x32_bf16(a, b, c, 0, 0, 0);
}
static __device__ __forceinline__ f32x4 mfma16h(f16x8 a, f16x8 b, f32x4 c) {
  return __builtin_amdgcn_mfma_f32_16x16x32_f16(a, b, c, 0, 0, 0);
}
static __device__ __forceinline__ float sigm(float x) { return 1.0f / (1.0f + __expf(-x)); }
static __device__ __forceinline__ float tanhf_(float x) {
  float e = __expf(-2.0f * fabsf(x));
  float t = (1.0f - e) / (1.0f + e);
  return x < 0.0f ? -t : t;
}
static __device__ __forceinline__ unsigned short ush(f16 h) {
  return __builtin_bit_cast(unsigned short, h);
}
static __device__ __forceinline__ f16 hus(unsigned short u) {
  return __builtin_bit_cast(f16, u);
}

// ---------------- prep kernels ----------------
__global__ void k_conv_wih(const float* __restrict__ W, bf16* __restrict__ hi,
                           bf16* __restrict__ lo) {
  int i = (blockIdx.x * 256 + threadIdx.x) * 4;
  f32x4 v = *(const f32x4*)(W + i);
#pragma unroll
  for (int j = 0; j < 4; ++j) {
    bf16 hh = (bf16)v[j];
    hi[i + j] = hh;
    lo[i + j] = (bf16)(v[j] - (float)hh);
  }
}

// Wtil = W_hh * gamma -> single f16 plane, fragment-linear:
// Wf[(ntg*8+kt)*64 + lane][8] = Wtil[g=ntg*16+(lane&15)][k=kt*32+(lane>>4)*8+j]
__global__ void k_prep_whh(const float* __restrict__ W, const float* __restrict__ gamma,
                           f16* __restrict__ Wf) {
  int tid = blockIdx.x * 256 + threadIdx.x;  // 0..32767
  int lane = tid & 63;
  int fk = tid >> 6;
  int ntg = fk >> 3, kt = fk & 7;
  int g = ntg * 16 + (lane & 15);
  int k = kt * 32 + ((lane >> 4) << 3);
  f16x8 r;
#pragma unroll
  for (int j = 0; j < 8; ++j) r[j] = (f16)(W[g * Hh + k + j] * gamma[k + j]);
  *(f16x8*)(Wf + (size_t)tid * 8) = r;
}

__global__ void k_prep_rd(const float* __restrict__ W, const float* __restrict__ gamma,
                          const float* __restrict__ beta, const float* __restrict__ bih,
                          const float* __restrict__ bhh, float* __restrict__ RD) {
  int g = blockIdx.x * 256 + threadIdx.x;  // 1024 total
  float r = 0.f, d = 0.f;
  for (int k = 0; k < Hh; ++k) {
    float w = W[g * Hh + k];
    r += w * gamma[k];
    d += w * beta[k];
  }
  RD[2 * g] = r;
  RD[2 * g + 1] = d + bih[g] + bhh[g];
}

// ---------------- xw GEMM (split-bf16) ----------------
__global__ __launch_bounds__(256, 2) void k_gemm(const float* __restrict__ x,
                                                 const bf16* __restrict__ Whi,
                                                 const bf16* __restrict__ Wlo,
                                                 float* __restrict__ xw,
                                                 int t0, int Tc, int ntb) {
  __shared__ bf16 Bs[2][128 * 128];
  int bid = blockIdx.x;
  int b = bid & 127;
  int r2 = bid >> 7;
  int tb = r2 % ntb;
  int gt = r2 / ntb;
  int g0 = gt * 128;
  int tid = threadIdx.x, w = tid >> 6, lane = tid & 63;
  int li = lane & 15, lg = lane >> 4;
  char* BsB = (char*)Bs;
  int tbase = tb * 128 + 32 * w;
  f32x4 acc[2][8];
#pragma unroll
  for (int mt = 0; mt < 2; ++mt)
#pragma unroll
    for (int nt = 0; nt < 8; ++nt) acc[mt][nt] = (f32x4){0.f, 0.f, 0.f, 0.f};

  for (int kp = 0; kp < 2; ++kp) {
#pragma unroll
    for (int it = 0; it < 8; ++it) {
      int p = it * 4096 + tid * 16;
      int row = p >> 8, colb = p & 255;
      size_t goff = (size_t)(g0 + row) * 512 + kp * 256 + colb;
      int dst = row * 256 + (colb ^ ((row & 7) << 4));
      *(bf16x8*)(BsB + dst) = *(const bf16x8*)((const char*)Whi + goff);
      *(bf16x8*)(BsB + 32768 + dst) = *(const bf16x8*)((const char*)Wlo + goff);
    }
    __syncthreads();
#pragma unroll
    for (int kt = 0; kt < 4; ++kt) {
      int kl = kt * 32 + lg * 8;
      int kgl = kp * 128 + kl;
      bf16x8 ah[2], al[2];
#pragma unroll
      for (int mt = 0; mt < 2; ++mt) {
        int t = t0 + tbase + 16 * mt + li;
        const float* xp = x + ((size_t)b * Ss + t) * Ii + kgl;
        f32x4 f0 = *(const f32x4*)xp;
        f32x4 f1 = *(const f32x4*)(xp + 4);
        bf16x8 hv, lv;
#pragma unroll
        for (int j = 0; j < 4; ++j) {
          bf16 h0 = (bf16)f0[j];
          hv[j] = h0;
          lv[j] = (bf16)(f0[j] - (float)h0);
          bf16 h1 = (bf16)f1[j];
          hv[4 + j] = h1;
          lv[4 + j] = (bf16)(f1[j] - (float)h1);
        }
        ah[mt] = hv;
        al[mt] = lv;
      }
#pragma unroll
      for (int nt = 0; nt < 8; ++nt) {
        int grow = nt * 16 + li;
        int off = grow * 256 + ((kl * 2) ^ ((grow & 7) << 4));
        bf16x8 bh = *(const bf16x8*)(BsB + off);
        bf16x8 bl = *(const bf16x8*)(BsB + 32768 + off);
#pragma unroll
        for (int mt = 0; mt < 2; ++mt) {
          acc[mt][nt] = mfma16b(ah[mt], bh, acc[mt][nt]);
          acc[mt][nt] = mfma16b(ah[mt], bl, acc[mt][nt]);
          acc[mt][nt] = mfma16b(al[mt], bh, acc[mt][nt]);
        }
      }
    }
    __syncthreads();
  }
#pragma unroll
  for (int mt = 0; mt < 2; ++mt)
#pragma unroll
    for (int nt = 0; nt < 8; ++nt)
#pragma unroll
      for (int r = 0; r < 4; ++r) {
        int tl = tbase + 16 * mt + lg * 4 + r;
        int g = g0 + nt * 16 + li;
        xw[((size_t)b * Tc + tl) * G4v + g] = acc[mt][nt][r];
      }
}

// ---------------- recurrence (quarter-split, paired-u64 exchange) ----------
// grid: 32 blocks, bid = q*8 + grp; block 256 thr / 4 waves.
__global__ __launch_bounds__(256, 1) void k_recur(
    const f16* __restrict__ Wf, const float* __restrict__ xw,
    const int* __restrict__ mask, const float* __restrict__ RD,
    float* __restrict__ st_h, float* __restrict__ st_c, float* __restrict__ st_o,
    u64* pub, float* __restrict__ out, int t0, int Tc, int first, int last) {
  __shared__ f16 hbH[16 * 256];     // h hi plane, byte ^= (row&7)<<4 swizzle
  __shared__ f16 hbL[16 * 256];     // h lo plane
  __shared__ float murs[2][16][2];  // (mu*rs, rs) per row, parity-buffered
  __shared__ float2 spw[4][16];     // per-wave per-row own-slice partials
  __shared__ float spart[16][16][2];  // init-path only
  int bid = blockIdx.x;
  int grp = bid & 7, q = bid >> 3;
  int tid = threadIdx.x, w = tid >> 6, lane = tid & 63;
  int li = lane & 15, lg = lane >> 4;
  int b0 = grp * 16;
  int jloc = (q * 4 + w) * 16 + li;
  char* hbHB = (char*)hbH;
  char* hbLB = (char*)hbL;

  // park this wave's W-quarter (single f16 plane, 128 regs) in AGPRs
  f16x8 wp[4][8];
#pragma unroll
  for (int c = 0; c < 4; ++c)
#pragma unroll
    for (int kt = 0; kt < 8; ++kt) {
      int ntg = c * 16 + q * 4 + w;
      wp[c][kt] = *(const f16x8*)(Wf + ((size_t)(ntg * 8 + kt) * 64 + lane) * 8);
      asm volatile("" : "+a"(wp[c][kt]));
    }
  float Rr[4], Dd[4];
#pragma unroll
  for (int c = 0; c < 4; ++c) {
    int g = c * 256 + jloc;
    Rr[c] = RD[2 * g];
    Dd[c] = RD[2 * g + 1];
  }

  float cst[4], ost[4];
  if (first) {
#pragma unroll
    for (int i = 0; i < 16; ++i) {
      hbH[tid * 16 + i] = (f16)0.0f;
      hbL[tid * 16 + i] = (f16)0.0f;
    }
#pragma unroll
    for (int r = 0; r < 4; ++r) { cst[r] = 0.f; ost[r] = 0.f; }
    if (tid < 16) { murs[0][tid][0] = 0.f; murs[0][tid][1] = rsqrtf(EPSF); }
  } else {
    int row = tid >> 4, cs = tid & 15, jseg = cs * 16;
    float s = 0.f, ss = 0.f;
#pragma unroll
    for (int i = 0; i < 16; ++i) {
      float v = st_h[(size_t)(b0 + row) * Hh + jseg + i];
      s += v;
      ss += v * v;
      f16 hh = (f16)v;
      int boff = row * 512 + (((jseg + i) * 2) ^ ((row & 7) << 4));
      *(f16*)(hbHB + boff) = hh;
      *(f16*)(hbLB + boff) = (f16)(v - (float)hh);
    }
    spart[row][cs][0] = s;
    spart[row][cs][1] = ss;
#pragma unroll
    for (int r = 0; r < 4; ++r) {
      int m = lg * 4 + r;
      cst[r] = st_c[(size_t)(b0 + m) * Hh + jloc];
      ost[r] = st_o[(size_t)(b0 + m) * Hh + jloc];
    }
    __syncthreads();
    if (tid < 16) {
      float s2 = 0.f, ss2 = 0.f;
#pragma unroll
      for (int i = 0; i < 16; ++i) { s2 += spart[tid][i][0]; ss2 += spart[tid][i][1]; }
      float mu = s2 * (1.f / 256.f);
      float var = ss2 * (1.f / 256.f) - mu * mu;
      float rs = rsqrtf(var + EPSF);
      murs[0][tid][0] = mu * rs;
      murs[0][tid][1] = rs;
    }
  }
  __syncthreads();

  // preload xw/mask for tl=0
  float xwv[4][4];
  int mk[4];
#pragma unroll
  for (int c = 0; c < 4; ++c)
#pragma unroll
    for (int r = 0; r < 4; ++r)
      xwv[c][r] = xw[((size_t)(b0 + lg * 4 + r) * Tc + 0) * G4v + c * 256 + jloc];
#pragma unroll
  for (int r = 0; r < 4; ++r) mk[r] = mask[(size_t)(b0 + lg * 4 + r) * Ss + t0];

  int grow = tid >> 4, gcg = tid & 15;  // gather role: row, col-quad (4 cols)

  for (int tl = 0; tl < Tc; ++tl) {
    int tg = t0 + tl;
    int slot = (tg + 1) & 1;
    u32 want = (u32)(tg + 1);

    // P1: two 8-deep MFMA chains per gate: (h_hi + h_lo) x W_f16
    f32x4 a0[4], a1[4];
#pragma unroll
    for (int c = 0; c < 4; ++c) {
      a0[c] = (f32x4){0.f, 0.f, 0.f, 0.f};
      a1[c] = (f32x4){0.f, 0.f, 0.f, 0.f};
    }
#pragma unroll
    for (int kt = 0; kt < 8; ++kt) {
      int aoff = li * 512 + (((kt * 32 + lg * 8) * 2) ^ ((li & 7) << 4));
      f16x8 ah = *(const f16x8*)(hbHB + aoff);
      f16x8 al = *(const f16x8*)(hbLB + aoff);
#pragma unroll
      for (int c = 0; c < 4; ++c) {
        a0[c] = mfma16h(ah, wp[c][kt], a0[c]);
        a1[c] = mfma16h(al, wp[c][kt], a1[c]);
      }
    }
    float mrs[4], rsv[4];
#pragma unroll
    for (int r = 0; r < 4; ++r) {
      int m = lg * 4 + r;
      mrs[r] = murs[tl & 1][m][0];
      rsv[r] = murs[tl & 1][m][1];
    }
    __syncthreads();  // SYNC_A: all waves done reading hb (state t) + murs

    // P2: gates -> c,h,out; own hb slice (hi+lo exact)
    float hnew[4];
#pragma unroll
    for (int r = 0; r < 4; ++r) {
      float i_ = (a0[0][r] + a1[0][r]) * rsv[r] - mrs[r] * Rr[0] + Dd[0] + xwv[0][r];
      float f_ = (a0[1][r] + a1[1][r]) * rsv[r] - mrs[r] * Rr[1] + Dd[1] + xwv[1][r];
      float g_ = (a0[2][r] + a1[2][r]) * rsv[r] - mrs[r] * Rr[2] + Dd[2] + xwv[2][r];
      float o_ = (a0[3][r] + a1[3][r]) * rsv[r] - mrs[r] * Rr[3] + Dd[3] + xwv[3][r];
      float cn = sigm(f_) * cst[r] + sigm(i_) * tanhf_(g_);
      float hn = sigm(o_) * tanhf_(cn);
      cst[r] = cn;
      ost[r] = mk[r] ? ost[r] : hn;
      hnew[r] = hn;
      int m = lg * 4 + r;
      f16 hh = (f16)hn;
      int boff = m * 512 + ((jloc * 2) ^ ((m & 7) << 4));
      *(f16*)(hbHB + boff) = hh;
      *(f16*)(hbLB + boff) = (f16)(hn - (float)hh);
    }
    // paired publish: even li packs (own col, odd-neighbor col) into one u64
    {
      u64* ph = pub + (size_t)(slot * 32 + bid) * 512;
#pragma unroll
      for (int r = 0; r < 4; ++r) {
        float ho = __shfl_xor(hnew[r], 1);  // all lanes participate
        if (!(li & 1)) {
          u64 pv = ((u64)want << 32) | ((u32)ush((f16)hnew[r]) << 16) |
                   (u32)ush((f16)ho);
          __hip_atomic_store(&ph[(lg * 4 + r) * 32 + w * 8 + (li >> 1)], pv,
                             __ATOMIC_RELAXED, __HIP_MEMORY_SCOPE_AGENT);
        }
      }
    }

    // issue first gather sweep (3 partners x 2 u64 = 4 cols per thread)
    u64 gv[3][2];
    const u64* srcs[3];
#pragma unroll
    for (int pi = 0; pi < 3; ++pi) {
      int qq = (q + 1 + pi) & 3;
      int pbid = qq * 8 + grp;
      srcs[pi] = pub + (size_t)(slot * 32 + pbid) * 512 + grow * 32 + gcg * 2;
      gv[pi][0] = __hip_atomic_load(&srcs[pi][0], __ATOMIC_RELAXED,
                                    __HIP_MEMORY_SCOPE_AGENT);
      gv[pi][1] = __hip_atomic_load(&srcs[pi][1], __ATOMIC_RELAXED,
                                    __HIP_MEMORY_SCOPE_AGENT);
    }

    // own-slice LN partials (shfl over the 16 li lanes)
    {
      float sr[4], qr[4];
#pragma unroll
      for (int r = 0; r < 4; ++r) { sr[r] = hnew[r]; qr[r] = hnew[r] * hnew[r]; }
#pragma unroll
      for (int msk = 1; msk < 16; msk <<= 1)
#pragma unroll
        for (int r = 0; r < 4; ++r) {
          sr[r] += __shfl_xor(sr[r], msk);
          qr[r] += __shfl_xor(qr[r], msk);
        }
      if (li == 0)
#pragma unroll
        for (int r = 0; r < 4; ++r) spw[w][lg * 4 + r] = make_float2(sr[r], qr[r]);
    }
    if (tl == Tc - 1) {
#pragma unroll
      for (int r = 0; r < 4; ++r) {
        int m = lg * 4 + r;
        st_h[(size_t)(b0 + m) * Hh + jloc] = hnew[r];
        st_c[(size_t)(b0 + m) * Hh + jloc] = cst[r];
        st_o[(size_t)(b0 + m) * Hh + jloc] = ost[r];
      }
      if (last) {
#pragma unroll
        for (int r = 0; r < 4; ++r) out[(size_t)(b0 + lg * 4 + r) * Hh + jloc] = ost[r];
      }
    }
    // prefetch next xw/mask (overlaps the poll window)
    {
      int tln = (tl + 1 < Tc) ? tl + 1 : Tc - 1;
#pragma unroll
      for (int c = 0; c < 4; ++c)
#pragma unroll
        for (int r = 0; r < 4; ++r)
          xwv[c][r] = xw[((size_t)(b0 + lg * 4 + r) * Tc + tln) * G4v + c * 256 + jloc];
#pragma unroll
      for (int r = 0; r < 4; ++r) mk[r] = mask[(size_t)(b0 + lg * 4 + r) * Ss + t0 + tln];
    }

    // P3: batch-sweep poll on the 6 tags
    {
      u32 bad = 0;
#pragma unroll
      for (int pi = 0; pi < 3; ++pi)
#pragma unroll
        for (int e = 0; e < 2; ++e) bad |= (u32)(gv[pi][e] >> 32) ^ want;
      int cnt = 0;
      while (bad) {
#pragma unroll
        for (int pi = 0; pi < 3; ++pi)
#pragma unroll
          for (int e = 0; e < 2; ++e)
            gv[pi][e] = __hip_atomic_load(&srcs[pi][e], __ATOMIC_RELAXED,
                                          __HIP_MEMORY_SCOPE_AGENT);
        bad = 0;
#pragma unroll
        for (int pi = 0; pi < 3; ++pi)
#pragma unroll
          for (int e = 0; e < 2; ++e) bad |= (u32)(gv[pi][e] >> 32) ^ want;
        if (++cnt > (1 << 20)) break;  // hang insurance
      }
    }
    // unpack -> hbH (f16), zero hbL; accumulate remote LN partials in regs
    float su = 0.f, qu = 0.f;
#pragma unroll
    for (int pi = 0; pi < 3; ++pi) {
      int qq = (q + 1 + pi) & 3;
      int j0 = qq * 64 + gcg * 4;
      int boff = grow * 512 + ((j0 * 2) ^ ((grow & 7) << 4));
      u32 d0 = (u32)gv[pi][0], d1 = (u32)gv[pi][1];
      f16x4 h4;
      h4[0] = hus((unsigned short)(d0 >> 16));
      h4[1] = hus((unsigned short)(d0 & 0xffffu));
      h4[2] = hus((unsigned short)(d1 >> 16));
      h4[3] = hus((unsigned short)(d1 & 0xffffu));
      f16x4 z4 = (f16x4){(f16)0.f, (f16)0.f, (f16)0.f, (f16)0.f};
      *(f16x4*)(hbHB + boff) = h4;
      *(f16x4*)(hbLB + boff) = z4;
#pragma unroll
      for (int e = 0; e < 4; ++e) {
        float f = (float)h4[e];
        su += f;
        qu += f * f;
      }
    }
#pragma unroll
    for (int msk = 1; msk < 16; msk <<= 1) {
      su += __shfl_xor(su, msk);
      qu += __shfl_xor(qu, msk);
    }
    __syncthreads();  // SYNC_D: hb complete; spw visible
    if (li == 0) {
      float s = su + spw[0][grow].x + spw[1][grow].x + spw[2][grow].x + spw[3][grow].x;
      float ss2 = qu + spw[0][grow].y + spw[1][grow].y + spw[2][grow].y + spw[3][grow].y;
      float mu = s * (1.f / 256.f);
      float var = ss2 * (1.f / 256.f) - mu * mu;
      float rs = rsqrtf(var + EPSF);
      murs[(tl + 1) & 1][grow][0] = mu * rs;
      murs[(tl + 1) & 1][grow][1] = rs;
    }
    __syncthreads();  // SYNC_E: murs write visible before next P1 reads it
  }
}

// ---------------- host ----------------
extern "C" void kernel_launch(void* const* d_in, const int* in_sizes, int n_in,
                              void* d_out, int out_size, void* d_ws, size_t ws_size,
                              hipStream_t stream) {
  (void)in_sizes; (void)n_in; (void)out_size;
  const float* x = (const float*)d_in[0];
  const int* mask = (const int*)d_in[1];
  const float* Wih = (const float*)d_in[2];
  const float* Whh = (const float*)d_in[3];
  const float* bih = (const float*)d_in[4];
  const float* bhh = (const float*)d_in[5];
  const float* gamma = (const float*)d_in[6];
  const float* beta = (const float*)d_in[7];
  float* outp = (float*)d_out;
  char* ws = (char*)d_ws;

  const size_t extra = 3 * (512u << 10) + (8u << 10) + 3 * (128u << 10) +
                       (256u << 10) + (64u << 10);
  int Tc = 128;
  if (ws_size >= (size_t)1024 * 524288 + extra) Tc = 1024;
  else if (ws_size >= (size_t)512 * 524288 + extra) Tc = 512;
  else if (ws_size >= (size_t)256 * 524288 + extra) Tc = 256;

  size_t o = 0;
  auto take = [&](size_t bytes) { size_t r = o; o += (bytes + 255) & ~(size_t)255; return r; };
  size_t xw_off = take((size_t)Bb * Tc * G4v * 4);
  size_t wihh_off = take(512u << 10);
  size_t wihl_off = take(512u << 10);
  size_t whh_off = take(512u << 10);
  size_t rd_off = take(8u << 10);
  size_t sth_off = take(128u << 10);
  size_t stc_off = take(128u << 10);
  size_t sto_off = take(128u << 10);
  size_t pub_off = take(256u << 10);

  bf16* wihh = (bf16*)(ws + wihh_off);
  bf16* wihl = (bf16*)(ws + wihl_off);
  f16* whhf = (f16*)(ws + whh_off);
  float* rd = (float*)(ws + rd_off);
  float* xwp = (float*)(ws + xw_off);
  float* sth = (float*)(ws + sth_off);
  float* stc = (float*)(ws + stc_off);
  float* sto = (float*)(ws + sto_off);
  u64* pubh = (u64*)(ws + pub_off);

  // clear pub tags (tag 0 < any step tag) -- removes all staleness hazards
  hipMemsetAsync(pubh, 0, 256u << 10, stream);
  k_conv_wih<<<dim3(256), dim3(256), 0, stream>>>(Wih, wihh, wihl);
  k_prep_whh<<<dim3(128), dim3(256), 0, stream>>>(Whh, gamma, whhf);
  k_prep_rd<<<dim3(4), dim3(256), 0, stream>>>(Whh, gamma, beta, bih, bhh, rd);

  int nchunk = Ss / Tc;
  int ntb = Tc / 128;
  for (int ci = 0; ci < nchunk; ++ci) {
    int t0 = ci * Tc;
    k_gemm<<<dim3(8 * ntb * 128), dim3(256), 0, stream>>>(x, wihh, wihl, xwp, t0, Tc, ntb);
    k_recur<<<dim3(32), dim3(256), 0, stream>>>(whhf, xwp, mask, rd, sth, stc, sto,
                                                pubh, outp, t0, Tc,
                                                ci == 0 ? 1 : 0, ci == nchunk - 1 ? 1 : 0);
  }
}